// Round 1
// baseline (568.420 us; speedup 1.0000x reference)
//
#include <hip/hip_runtime.h>

// MHA forward, MI355X/gfx950.
// Plan: bf16-cast everything -> mfma_f32_16x16x32_bf16 for all 4 GEMMs.
//   K1: QKV = X @ Wqkv^T + b (q pre-scaled by 1/8), bf16 out, 128x128 tile GEMM
//   K2: fused per (b,h,64 q rows): pass1 row-sum of exp(S); pass2 recompute S,
//       write probs*8 (fp32, once, never re-read), PV accumulate -> attn bf16
//   K3: out = attn @ out_w^T + out_b, fp32 out
// LDS XOR-swizzle (T2) everywhere; global_load_lds with pre-swizzled global src.

#define DEV __device__ __forceinline__

typedef __attribute__((ext_vector_type(8))) short short8;   // 8 bf16 = 4 VGPRs (MFMA A/B frag)
typedef __attribute__((ext_vector_type(4))) float f32x4;    // MFMA C/D frag

DEV unsigned short f2b(float f) {   // f32 -> bf16, round-nearest-even
  union { float f; unsigned u; } v; v.f = f;
  unsigned r = v.u + 0x7fffu + ((v.u >> 16) & 1u);
  return (unsigned short)(r >> 16);
}

DEV void gl_lds16(const void* g, void* l) {  // async global->LDS; HW dest = l + lane*16
  __builtin_amdgcn_global_load_lds(
      (const __attribute__((address_space(1))) void*)g,
      (__attribute__((address_space(3))) void*)l, 16, 0, 0);
}

__global__ void cvt_f32_bf16(const float* __restrict__ src, unsigned short* __restrict__ dst, int n) {
  int i = (blockIdx.x * blockDim.x + threadIdx.x) * 4;
  if (i >= n) return;
  float4 v = *(const float4*)(src + i);
  ushort4 o;
  o.x = f2b(v.x); o.y = f2b(v.y); o.z = f2b(v.z); o.w = f2b(v.w);
  *(ushort4*)(dst + i) = o;
}

// C = A @ B^T + bias; A[M][K], B[N][K] bf16 row-major. 128x128 tile, BK=64,
// 256 threads = 4 waves (2x2, 64x64 each). Swizzled LDS via pre-swizzled gload_lds src.
template<bool BF16OUT, bool QSCALE>
__global__ __launch_bounds__(256, 2) void gemm_bt_kernel(
    const unsigned short* __restrict__ A,
    const unsigned short* __restrict__ B,
    const float* __restrict__ bias,
    void* __restrict__ Cout,
    int M, int N, int K, int scaleCols)
{
  constexpr int BM = 128, BK = 64;
  (void)M; (void)BM;
  __shared__ __align__(16) unsigned short As[128*BK];
  __shared__ __align__(16) unsigned short Bs[128*BK];
  const int tid = threadIdx.x, lane = tid & 63, wid = tid >> 6;
  const int lhi = lane >> 4, llo = lane & 15;
  const int m0 = blockIdx.y * 128, n0 = blockIdx.x * 128;
  const int wr = wid >> 1, wc = wid & 1;

  f32x4 acc[4][4] = {};

  const int nsteps = K / BK;
  for (int kt = 0; kt < nsteps; ++kt) {
    __syncthreads();   // protect LDS from overwrite while prior iter still reading
#pragma unroll
    for (int s = 0; s < 4; ++s) {
      int u = wid*4 + s;                 // 16 KB tile = 16 units of 1KB
      int a = u*1024 + lane*16;          // linear LDS byte this lane fills
      int t = a >> 7;                    // tile row (128B rows)
      int cb = (a & 127) ^ ((t & 7) << 4); // true byte-in-row (XOR-swizzle inverse)
      int e = kt*BK + (cb >> 1);         // element offset in global row
      gl_lds16(A + (size_t)(m0 + t)*K + e, (char*)As + u*1024);
      gl_lds16(B + (size_t)(n0 + t)*K + e, (char*)Bs + u*1024);
    }
    __syncthreads();
#pragma unroll
    for (int kk = 0; kk < 2; ++kk) {
      short8 af[4], bfr[4];
#pragma unroll
      for (int mf = 0; mf < 4; ++mf) {
        int row = wr*64 + mf*16 + llo;
        af[mf] = *(const short8*)((const char*)As + row*128 + ((kk*64 + lhi*16) ^ ((row & 7) << 4)));
      }
#pragma unroll
      for (int nf = 0; nf < 4; ++nf) {
        int row = wc*64 + nf*16 + llo;
        bfr[nf] = *(const short8*)((const char*)Bs + row*128 + ((kk*64 + lhi*16) ^ ((row & 7) << 4)));
      }
#pragma unroll
      for (int mf = 0; mf < 4; ++mf)
#pragma unroll
        for (int nf = 0; nf < 4; ++nf)
          acc[mf][nf] = __builtin_amdgcn_mfma_f32_16x16x32_bf16(af[mf], bfr[nf], acc[mf][nf], 0, 0, 0);
    }
  }
  // epilogue: C/D layout col=lane&15, row=(lane>>4)*4+r (m89-verified)
#pragma unroll
  for (int mf = 0; mf < 4; ++mf)
#pragma unroll
    for (int nf = 0; nf < 4; ++nf) {
      int n = n0 + wc*64 + nf*16 + llo;
      float bv = bias[n];
      float sc = (QSCALE && n < scaleCols) ? 0.125f : 1.0f;
#pragma unroll
      for (int r = 0; r < 4; ++r) {
        int m = m0 + wr*64 + mf*16 + lhi*4 + r;
        float val = (acc[mf][nf][r] + bv) * sc;
        if (BF16OUT) ((unsigned short*)Cout)[(size_t)m*N + n] = f2b(val);
        else         ((float*)Cout)[(size_t)m*N + n] = val;
      }
    }
}

// Fused attention: block = (b,h,qt): 64 q-rows, 256 threads (4 waves).
// Wave w owns t-columns [w*32, w*32+32) of each 128-t tile for scores,
// and q-rows [w*16, w*16+16) for PV.
__global__ __launch_bounds__(256, 2) void mha_fused_kernel(
    const unsigned short* __restrict__ qkv,   // [8192][3072] bf16, q pre-scaled
    float* __restrict__ probs,                // [64][2048][2048] f32 = probs/scale
    unsigned short* __restrict__ attnb)       // [8192][1024] bf16
{
  constexpr int T = 2048, E3 = 3072, QB = 64, TB = 128, NT = T / TB;
  __shared__ __align__(16) unsigned short Qs[QB*64];   //  8 KB, 128B rows, swz
  __shared__ __align__(16) unsigned short Ks[TB*64];   // 16 KB, 128B rows, swz
  __shared__ __align__(16) unsigned short Vt[64*TB];   // 16 KB, V transposed, 256B rows, swz
  __shared__ __align__(16) unsigned short Ps[QB*TB];   // 16 KB, 256B rows, swz
  __shared__ __align__(16) float lsum[4][QB];
  __shared__ __align__(16) float linv[QB];

  const int tid = threadIdx.x, lane = tid & 63, wid = tid >> 6;
  const int lhi = lane >> 4, llo = lane & 15;
  const int qt = blockIdx.x & 31, bh = blockIdx.x >> 5;
  const int b = bh >> 4, h = bh & 15;
  const int q0 = qt * QB;
  const size_t tokQ = (size_t)b*T + q0;

  // stage Q once (8 KB = 8 units)
#pragma unroll
  for (int s = 0; s < 2; ++s) {
    int u = wid*2 + s;
    int a = u*1024 + lane*16;
    int t = a >> 7;
    int cb = (a & 127) ^ ((t & 7) << 4);
    gl_lds16(qkv + (tokQ + t)*E3 + h*64 + (cb >> 1), (char*)Qs + u*1024);
  }

  float part[4][4] = {};   // per-lane partial row sums of exp(S)

  // ---------------- pass 1: denominators ----------------
  for (int tt = 0; tt < NT; ++tt) {
    __syncthreads();
    const size_t tokK = (size_t)b*T + tt*TB;
#pragma unroll
    for (int s = 0; s < 4; ++s) {
      int u = wid*4 + s;
      int a = u*1024 + lane*16;
      int t = a >> 7;
      int cb = (a & 127) ^ ((t & 7) << 4);
      gl_lds16(qkv + (tokK + t)*E3 + 1024 + h*64 + (cb >> 1), (char*)Ks + u*1024);
    }
    __syncthreads();
    f32x4 sacc[4][2] = {};
#pragma unroll
    for (int kk = 0; kk < 2; ++kk) {
      short8 af[4], bfr[2];
#pragma unroll
      for (int qf = 0; qf < 4; ++qf) {
        int row = qf*16 + llo;
        af[qf] = *(const short8*)((const char*)Qs + row*128 + ((kk*64 + lhi*16) ^ ((row & 7) << 4)));
      }
#pragma unroll
      for (int tf = 0; tf < 2; ++tf) {
        int row = wid*32 + tf*16 + llo;
        bfr[tf] = *(const short8*)((const char*)Ks + row*128 + ((kk*64 + lhi*16) ^ ((row & 7) << 4)));
      }
#pragma unroll
      for (int qf = 0; qf < 4; ++qf)
#pragma unroll
        for (int tf = 0; tf < 2; ++tf)
          sacc[qf][tf] = __builtin_amdgcn_mfma_f32_16x16x32_bf16(af[qf], bfr[tf], sacc[qf][tf], 0, 0, 0);
    }
#pragma unroll
    for (int qf = 0; qf < 4; ++qf)
#pragma unroll
      for (int tf = 0; tf < 2; ++tf)
#pragma unroll
        for (int r = 0; r < 4; ++r)
          part[qf][r] += __expf(sacc[qf][tf][r]);
  }

  // reduce 16 col-lanes, then combine 4 waves via LDS
#pragma unroll
  for (int qf = 0; qf < 4; ++qf)
#pragma unroll
    for (int r = 0; r < 4; ++r) {
      float v = part[qf][r];
      v += __shfl_xor(v, 1);
      v += __shfl_xor(v, 2);
      v += __shfl_xor(v, 4);
      v += __shfl_xor(v, 8);
      if (llo == 0) lsum[wid][qf*16 + lhi*4 + r] = v;
    }
  __syncthreads();
  if (tid < QB) linv[tid] = 1.0f / (lsum[0][tid] + lsum[1][tid] + lsum[2][tid] + lsum[3][tid]);
  __syncthreads();
  float lrr[4][4];
#pragma unroll
  for (int qf = 0; qf < 4; ++qf) {
    float4 t4 = *(const float4*)&linv[qf*16 + lhi*4];
    lrr[qf][0] = t4.x; lrr[qf][1] = t4.y; lrr[qf][2] = t4.z; lrr[qf][3] = t4.w;
  }

  // ---------------- pass 2: probs out + PV ----------------
  f32x4 pv[4] = {};
  for (int tt = 0; tt < NT; ++tt) {
    __syncthreads();
    const size_t tokK = (size_t)b*T + tt*TB;
#pragma unroll
    for (int s = 0; s < 4; ++s) {
      int u = wid*4 + s;
      int a = u*1024 + lane*16;
      int t = a >> 7;
      int cb = (a & 127) ^ ((t & 7) << 4);
      gl_lds16(qkv + (tokK + t)*E3 + 1024 + h*64 + (cb >> 1), (char*)Ks + u*1024);
    }
    // V tile, reg-staged transpose into Vt[d][t] (swizzled)
#pragma unroll
    for (int s = 0; s < 4; ++s) {
      int chunk = s*256 + tid;
      int t = chunk >> 3, c = chunk & 7;
      uint4 vv = *(const uint4*)(qkv + (tokK + t)*E3 + 2048 + h*64 + c*8);
      const unsigned short* u16 = (const unsigned short*)&vv;
#pragma unroll
      for (int j = 0; j < 8; ++j) {
        int d = c*8 + j;
        *(unsigned short*)((char*)Vt + d*256 + ((t*2) ^ ((d & 7) << 4))) = u16[j];
      }
    }
    __syncthreads();
    f32x4 sacc[4][2] = {};
#pragma unroll
    for (int kk = 0; kk < 2; ++kk) {
      short8 af[4], bfr[2];
#pragma unroll
      for (int qf = 0; qf < 4; ++qf) {
        int row = qf*16 + llo;
        af[qf] = *(const short8*)((const char*)Qs + row*128 + ((kk*64 + lhi*16) ^ ((row & 7) << 4)));
      }
#pragma unroll
      for (int tf = 0; tf < 2; ++tf) {
        int row = wid*32 + tf*16 + llo;
        bfr[tf] = *(const short8*)((const char*)Ks + row*128 + ((kk*64 + lhi*16) ^ ((row & 7) << 4)));
      }
#pragma unroll
      for (int qf = 0; qf < 4; ++qf)
#pragma unroll
        for (int tf = 0; tf < 2; ++tf)
          sacc[qf][tf] = __builtin_amdgcn_mfma_f32_16x16x32_bf16(af[qf], bfr[tf], sacc[qf][tf], 0, 0, 0);
    }
    // probs (fp32, *8) + P tile (bf16, normalized) to LDS
#pragma unroll
    for (int qf = 0; qf < 4; ++qf)
#pragma unroll
      for (int tf = 0; tf < 2; ++tf)
#pragma unroll
        for (int r = 0; r < 4; ++r) {
          float e = __expf(sacc[qf][tf][r]);
          float p = e * lrr[qf][r];
          int ql = qf*16 + lhi*4 + r;
          int tl = wid*32 + tf*16 + llo;
          probs[((size_t)bh*T + (q0 + ql))*T + (tt*TB + tl)] = 8.0f * p;
          *(unsigned short*)((char*)Ps + ql*256 + ((tl*2) ^ ((ql & 7) << 4))) = f2b(p);
        }
    __syncthreads();
    // PV: wave w computes q-rows [w*16, w*16+16), all 64 d
#pragma unroll
    for (int kk2 = 0; kk2 < 4; ++kk2) {
      int rowp = wid*16 + llo;
      int bIn = kk2*64 + lhi*16;
      short8 pa = *(const short8*)((const char*)Ps + rowp*256 + (bIn ^ ((rowp & 7) << 4)));
#pragma unroll
      for (int nf = 0; nf < 4; ++nf) {
        int rowd = nf*16 + llo;
        short8 vb = *(const short8*)((const char*)Vt + rowd*256 + (bIn ^ ((rowd & 7) << 4)));
        pv[nf] = __builtin_amdgcn_mfma_f32_16x16x32_bf16(pa, vb, pv[nf], 0, 0, 0);
      }
    }
  }
#pragma unroll
  for (int nf = 0; nf < 4; ++nf)
#pragma unroll
    for (int r = 0; r < 4; ++r) {
      int ql = wid*16 + lhi*4 + r;
      int d = nf*16 + llo;
      attnb[(tokQ + ql)*1024 + h*64 + d] = f2b(pv[nf][r]);
    }
}

extern "C" void kernel_launch(void* const* d_in, const int* in_sizes, int n_in,
                              void* d_out, int out_size, void* d_ws, size_t ws_size,
                              hipStream_t stream) {
  (void)in_sizes; (void)n_in; (void)out_size; (void)ws_size;
  const float* x    = (const float*)d_in[0];
  const float* wqkv = (const float*)d_in[1];
  const float* bqkv = (const float*)d_in[2];
  const float* wout = (const float*)d_in[3];
  const float* bout = (const float*)d_in[4];

  constexpr int B = 4, T = 2048, E = 1024, H = 16;
  constexpr int M = B * T;                    // 8192 tokens
  constexpr size_t NX   = (size_t)M * E;      // 8,388,608
  constexpr size_t NW1  = (size_t)3 * E * E;  // 3,145,728
  constexpr size_t NW2  = (size_t)E * E;      // 1,048,576
  constexpr size_t NQKV = (size_t)M * 3 * E;  // 25,165,824

  char* ws = (char*)d_ws;                     // total ws use ≈ 92.3 MB
  unsigned short* xb    = (unsigned short*)ws;  ws += NX * 2;
  unsigned short* wqkvb = (unsigned short*)ws;  ws += NW1 * 2;
  unsigned short* woutb = (unsigned short*)ws;  ws += NW2 * 2;
  unsigned short* qkvb  = (unsigned short*)ws;  ws += NQKV * 2;
  unsigned short* attnb = (unsigned short*)ws;  ws += NX * 2;

  cvt_f32_bf16<<<(int)(NX  / 1024), 256, 0, stream>>>(x,    xb,    (int)NX);
  cvt_f32_bf16<<<(int)(NW1 / 1024), 256, 0, stream>>>(wqkv, wqkvb, (int)NW1);
  cvt_f32_bf16<<<(int)(NW2 / 1024), 256, 0, stream>>>(wout, woutb, (int)NW2);

  // QKV projection: [8192,3072] = X @ Wqkv^T + b, q-cols (<1024) scaled by 1/8
  gemm_bt_kernel<true, true><<<dim3(3*E/128, M/128), 256, 0, stream>>>(
      xb, wqkvb, bqkv, qkvb, M, 3*E, E, E);

  // fused scores/softmax/probs-out/PV
  float* probsOut = (float*)d_out + NX;
  mha_fused_kernel<<<B*H*(T/64), 256, 0, stream>>>(qkvb, probsOut, attnb);

  // out = attn @ out_w^T + out_b (fp32)
  gemm_bt_kernel<false, false><<<dim3(E/128, M/128), 256, 0, stream>>>(
      attnb, woutb, bout, (float*)d_out, M, E, E, 0);
}